// Round 1
// 249.988 us; speedup vs baseline: 1.0051x; 1.0051x over previous
//
#include <hip/hip_runtime.h>
#include <math.h>

// Problem constants
#define SB 4
#define SS 2048
#define SD 1024
#define SH 16
#define SHD 64
#define SM (SB * SS) // 8192 rows

using f32x4 = __attribute__((ext_vector_type(4))) float;
using h8    = __attribute__((ext_vector_type(8))) _Float16;
using h4    = __attribute__((ext_vector_type(4))) _Float16;
using fp16x2 = __fp16 __attribute__((ext_vector_type(2)));
using fp16x4 = __fp16 __attribute__((ext_vector_type(4)));
using u32x4 = __attribute__((ext_vector_type(4))) unsigned int;
using u64x2 = __attribute__((ext_vector_type(2))) unsigned long long;

__device__ __forceinline__ unsigned short f2h(float x) {
  _Float16 h = (_Float16)x;
  return __builtin_bit_cast(unsigned short, h);
}

__device__ __forceinline__ void gld_lds16(const unsigned short* g, unsigned short* l) {
  __builtin_amdgcn_global_load_lds(
      (const __attribute__((address_space(1))) unsigned int*)g,
      (__attribute__((address_space(3))) unsigned int*)l, 16, 0, 0);
}

// ---------------- fp32 -> fp16 convert (4 elems/thread) ----------------
__global__ __launch_bounds__(256) void cvt4h(const float* __restrict__ in,
                                             unsigned short* __restrict__ out, int n4) {
  int i = blockIdx.x * 256 + threadIdx.x;
  if (i >= n4) return;
  float4 v = ((const float4*)in)[i];
  unsigned long long r = (unsigned long long)f2h(v.x)
                       | ((unsigned long long)f2h(v.y) << 16)
                       | ((unsigned long long)f2h(v.z) << 32)
                       | ((unsigned long long)f2h(v.w) << 48);
  ((unsigned long long*)out)[i] = r;
}

// three weight converts in one dispatch
__global__ __launch_bounds__(256) void cvt3w(const float* __restrict__ w0, const float* __restrict__ w1,
                                             const float* __restrict__ w2,
                                             unsigned short* __restrict__ o0, unsigned short* __restrict__ o1,
                                             unsigned short* __restrict__ o2) {
  const int z = blockIdx.y;
  const float* in = (z == 0) ? w0 : (z == 1) ? w1 : w2;
  unsigned short* out = (z == 0) ? o0 : (z == 1) ? o1 : o2;
  int i = blockIdx.x * 256 + threadIdx.x;
  float4 v = ((const float4*)in)[i];
  unsigned long long r = (unsigned long long)f2h(v.x)
                       | ((unsigned long long)f2h(v.y) << 16)
                       | ((unsigned long long)f2h(v.z) << 32)
                       | ((unsigned long long)f2h(v.w) << 48);
  ((unsigned long long*)out)[i] = r;
}

// ---------------- fused QKV projection GEMM, BK=64, XCD-swizzled ----------------
// z==0: Qh = (X@Wq^T + bq) * (1/8*log2e)  fp16, [s][1024]   (swapped-operand path)
// z==1: Kh =  X@Wk^T + bk                 fp16, [s][1024]   (swapped-operand path)
// z==2: Vt =  X@Wv^T + bv                 fp16, transposed [bh*64+d][s]
__global__ __launch_bounds__(256) void gemm_qkv(
    const unsigned short* __restrict__ Xh,
    const unsigned short* __restrict__ Wqh, const unsigned short* __restrict__ Wkh,
    const unsigned short* __restrict__ Wvh,
    const float* __restrict__ bq, const float* __restrict__ bk, const float* __restrict__ bv,
    unsigned short* __restrict__ Qh, unsigned short* __restrict__ Kh,
    unsigned short* __restrict__ Vt) {
  __shared__ unsigned short lA[128 * 64]; // 16 KB
  __shared__ unsigned short lB[128 * 64]; // 16 KB
  const int L = blockIdx.x;
  const int xcd = L & 7, rr = L >> 3;
  const int mloc = rr & 7, widx = rr >> 3;   // widx 0..23
  const int tNi = widx & 7, z = widx >> 3;   // z 0..2
  const int tM = (xcd * 8 + mloc) * 128, tN = tNi * 128;

  const unsigned short* W = (z == 0) ? Wqh : (z == 1) ? Wkh : Wvh;
  const float* bias = (z == 0) ? bq : (z == 1) ? bk : bv;

  const int tid = threadIdx.x;
  const int wave = tid >> 6, lane = tid & 63;
  const int quad = lane >> 4, l16 = lane & 15;
  const int wr = (wave >> 1) * 64, wc = (wave & 1) * 64;

  f32x4 acc[4][4] = {};

  const int rB = tid >> 3;
  const int colOff = (((tid & 7) ^ (rB & 7))) * 8;
  const unsigned short* gA[4];
  const unsigned short* gB[4];
#pragma unroll
  for (int i = 0; i < 4; ++i) {
    gA[i] = Xh + (size_t)(tM + i * 32 + rB) * SD + colOff;
    gB[i] = W  + (size_t)(tN + i * 32 + rB) * SD + colOff;
  }
  unsigned short* dA[4];
  unsigned short* dB[4];
#pragma unroll
  for (int i = 0; i < 4; ++i) {
    dA[i] = lA + (i * 256 + wave * 64) * 8;
    dB[i] = lB + (i * 256 + wave * 64) * 8;
  }
  const int swl = l16 & 7;

  if (z == 2) {
    for (int k0 = 0; k0 < SD; k0 += 64) {
      __syncthreads();
#pragma unroll
      for (int i = 0; i < 4; ++i) gld_lds16(gA[i] + k0, dA[i]);
#pragma unroll
      for (int i = 0; i < 4; ++i) gld_lds16(gB[i] + k0, dB[i]);
      __syncthreads();
#pragma unroll
      for (int ks = 0; ks < 2; ++ks) {
        h8 af[4], bf[4];
#pragma unroll
        for (int mi = 0; mi < 4; ++mi)
          af[mi] = *(const h8*)(lA + (wr + mi * 16 + l16) * 64 + (((ks * 4 + quad) ^ swl) * 8));
#pragma unroll
        for (int ni = 0; ni < 4; ++ni)
          bf[ni] = *(const h8*)(lB + (wc + ni * 16 + l16) * 64 + (((ks * 4 + quad) ^ swl) * 8));
#pragma unroll
        for (int mi = 0; mi < 4; ++mi)
#pragma unroll
          for (int ni = 0; ni < 4; ++ni)
            acc[mi][ni] = __builtin_amdgcn_mfma_f32_16x16x32_f16(af[mi], bf[ni], acc[mi][ni], 0, 0, 0);
      }
    }
    // C/D: col=l16 -> gn, row=quad*4+r -> gm (s-direction) ; pack r -> b64
#pragma unroll
    for (int ni = 0; ni < 4; ++ni) {
      const int gn = tN + wc + ni * 16 + l16;
      const float bb = bias[gn];
#pragma unroll
      for (int mi = 0; mi < 4; ++mi) {
        const int gm = tM + wr + mi * 16 + quad * 4;
        const int vb = gm >> 11, vs = gm & 2047;
        unsigned long long wv = 0;
#pragma unroll
        for (int r = 0; r < 4; ++r)
          wv |= (unsigned long long)f2h(acc[mi][ni][r] + bb) << (16 * r);
        *(unsigned long long*)(Vt + (size_t)(vb * 1024 + gn) * SS + vs) = wv;
      }
    }
  } else {
    // swapped operands: D m-dim = W rows (gn), n-dim = X rows (gm)
    for (int k0 = 0; k0 < SD; k0 += 64) {
      __syncthreads();
#pragma unroll
      for (int i = 0; i < 4; ++i) gld_lds16(gA[i] + k0, dA[i]);
#pragma unroll
      for (int i = 0; i < 4; ++i) gld_lds16(gB[i] + k0, dB[i]);
      __syncthreads();
#pragma unroll
      for (int ks = 0; ks < 2; ++ks) {
        h8 af[4], bf[4];
#pragma unroll
        for (int mi = 0; mi < 4; ++mi)
          af[mi] = *(const h8*)(lA + (wr + mi * 16 + l16) * 64 + (((ks * 4 + quad) ^ swl) * 8));
#pragma unroll
        for (int ni = 0; ni < 4; ++ni)
          bf[ni] = *(const h8*)(lB + (wc + ni * 16 + l16) * 64 + (((ks * 4 + quad) ^ swl) * 8));
#pragma unroll
        for (int mi = 0; mi < 4; ++mi)
#pragma unroll
          for (int ni = 0; ni < 4; ++ni)
            acc[mi][ni] = __builtin_amdgcn_mfma_f32_16x16x32_f16(bf[ni], af[mi], acc[mi][ni], 0, 0, 0);
      }
    }
    // C/D: col=l16 -> gm (X row), row=quad*4+r -> gn (consecutive!) -> b64 store
    const float sc = (z == 0) ? 0.18033688011112042f : 1.0f; // 1/8*log2(e)
    unsigned short* C = (z == 0) ? Qh : Kh;
#pragma unroll
    for (int mi = 0; mi < 4; ++mi) {
      const int gm = tM + wr + mi * 16 + l16;
#pragma unroll
      for (int ni = 0; ni < 4; ++ni) {
        const int gnb = tN + wc + ni * 16 + quad * 4;
        const float4 bb4 = *(const float4*)(bias + gnb);
        unsigned long long wv;
        wv  = (unsigned long long)f2h((acc[mi][ni][0] + bb4.x) * sc);
        wv |= (unsigned long long)f2h((acc[mi][ni][1] + bb4.y) * sc) << 16;
        wv |= (unsigned long long)f2h((acc[mi][ni][2] + bb4.z) * sc) << 32;
        wv |= (unsigned long long)f2h((acc[mi][ni][3] + bb4.w) * sc) << 48;
        *(unsigned long long*)(C + (size_t)gm * SD + gnb) = wv;
      }
    }
  }
}

// ---------------- attention: 128 q/block, 32 q/wave, K=32 PV, P fully in-register ----
// S^T = K·Q^T (A=K-frag K=32, B=Q-frag) -> C: col=l16=query, row=nt*16+quad*4+r=key
// P redistribution WITHOUT LDS: one v_permlane32_swap per packed pair puts, at lane
// quad q, keys {q0:0-3,8-11 | q1:4-7,12-15 | q2:16-19,24-27 | q3:20-23,28-31} into the
// PV B-operand k-slots. MFMA k-slots are positional, so this is valid as long as the
// V A-operand is read with the SAME key->slot map: 4x ds_read_b64 per f at nibble
// offsets (chunk 2*(q>>1)(+1)(+4), half q&1), XOR-swizzled like the staging layout.
__global__ __launch_bounds__(256, 4) void attn(const unsigned short* __restrict__ Qh,
                                               const unsigned short* __restrict__ Kh,
                                               const unsigned short* __restrict__ Vt,
                                               float* __restrict__ out) {
  __shared__ unsigned short lK[2][64 * 64]; // 16 KB
  __shared__ unsigned short lV[2][64 * 64]; // 16 KB   (no P LDS: 32 KB total)
  const int tid = threadIdx.x;
  const int wave = tid >> 6, lane = tid & 63;
  const int quad = lane >> 4, l16 = lane & 15;
  // XCD swizzle: all 16 q-tiles of one bh share an XCD (bid%8 == bh%8)
  const int bid = blockIdx.x;                      // grid 1024
  const int bh = (bid & 7) | (((bid >> 3) & 7) << 3);
  const int qt = bid >> 6;                         // 0..15
  const int b = bh >> 4, h = bh & 15;
  const int qsA = qt * 128 + wave * 16;            // half B = qsA + 64

  const unsigned short* qpA = Qh + ((size_t)(b * SS + qsA + l16)) * SD + h * 64 + quad * 8;
  const unsigned short* qpB = qpA + (size_t)64 * SD;
  h8 aqA0 = *(const h8*)(qpA);
  h8 aqA1 = *(const h8*)(qpA + 32);
  h8 aqB0 = *(const h8*)(qpB);
  h8 aqB1 = *(const h8*)(qpB + 32);

  const int row0 = tid >> 3, cs0 = (tid & 7) ^ (row0 & 7);
  const int row1 = row0 + 32, cs1 = (tid & 7) ^ (row1 & 7);
  const unsigned short* kS0 = Kh + ((size_t)(b * SS + row0)) * SD + h * 64 + cs0 * 8;
  const unsigned short* kS1 = Kh + ((size_t)(b * SS + row1)) * SD + h * 64 + cs1 * 8;
  const unsigned short* vS0 = Vt + ((size_t)(bh * 64 + row0)) * SS + cs0 * 8;
  const unsigned short* vS1 = Vt + ((size_t)(bh * 64 + row1)) * SS + cs1 * 8;
  unsigned short* dK0 = &lK[0][wave * 512];
  unsigned short* dK1 = &lK[0][2048 + wave * 512];
  unsigned short* dV0 = &lV[0][wave * 512];
  unsigned short* dV1 = &lV[0][2048 + wave * 512];

  f32x4 ovA[4] = {}, ovB[4] = {};
  float l_accA = 0.f, l_accB = 0.f;
  const int swl = l16 & 15 & 7;
  const int Q2 = quad >> 1, hq = quad & 1;
  // K-frag chunk offsets (canonical layout, unchanged)
  const int ko0 = (quad ^ swl) * 8, ko1 = ((4 + quad) ^ swl) * 8;
  // V-frag nibble offsets matching the permlane key->slot map (shorts)
  const int vo0 = ((2 * Q2) ^ swl) * 8 + hq * 4;
  const int vo1 = ((2 * Q2 + 1) ^ swl) * 8 + hq * 4;
  const int vo2 = ((4 + 2 * Q2) ^ swl) * 8 + hq * 4;
  const int vo3 = ((5 + 2 * Q2) ^ swl) * 8 + hq * 4;

  gld_lds16(kS0, dK0); gld_lds16(kS1, dK1);
  gld_lds16(vS0, dV0); gld_lds16(vS1, dV1);
  kS0 += 64 * SD; kS1 += 64 * SD; vS0 += 64; vS1 += 64;

  for (int kt = 0; kt < 32; ++kt) {
    const int buf = kt & 1;
    __syncthreads();
    if (kt < 31) {
      const int o = (buf ^ 1) * 64 * 64;
      gld_lds16(kS0, dK0 + o); gld_lds16(kS1, dK1 + o);
      gld_lds16(vS0, dV0 + o); gld_lds16(vS1, dV1 + o);
      kS0 += 64 * SD; kS1 += 64 * SD; vS0 += 64; vS1 += 64;
    }
    const unsigned short* Kt = lK[buf];
    const unsigned short* Vl = lV[buf];

    // QK^T: 16 MFMA K=32 (K-frags shared by both query halves)
    f32x4 sA[4], sB[4];
#pragma unroll
    for (int nt = 0; nt < 4; ++nt) {
      const unsigned short* kr = Kt + (nt * 16 + l16) * 64;
      h8 kf0 = *(const h8*)(kr + ko0);
      h8 kf1 = *(const h8*)(kr + ko1);
      f32x4 zA = {};
      zA = __builtin_amdgcn_mfma_f32_16x16x32_f16(kf0, aqA0, zA, 0, 0, 0);
      sA[nt] = __builtin_amdgcn_mfma_f32_16x16x32_f16(kf1, aqA1, zA, 0, 0, 0);
      f32x4 zB = {};
      zB = __builtin_amdgcn_mfma_f32_16x16x32_f16(kf0, aqB0, zB, 0, 0, 0);
      sB[nt] = __builtin_amdgcn_mfma_f32_16x16x32_f16(kf1, aqB1, zB, 0, 0, 0);
    }

    // half A: exp/pack -> in-register key redistribution (no LDS)
    unsigned ulA[4], uhA[4];
#pragma unroll
    for (int g = 0; g < 4; ++g) {
      float p0 = __builtin_amdgcn_exp2f(sA[g][0]);
      float p1 = __builtin_amdgcn_exp2f(sA[g][1]);
      float p2 = __builtin_amdgcn_exp2f(sA[g][2]);
      float p3 = __builtin_amdgcn_exp2f(sA[g][3]);
      l_accA += (p0 + p1) + (p2 + p3);
      ulA[g] = __builtin_bit_cast(unsigned, __builtin_amdgcn_cvt_pkrtz(p0, p1));
      uhA[g] = __builtin_bit_cast(unsigned, __builtin_amdgcn_cvt_pkrtz(p2, p3));
    }
    auto aA0 = __builtin_amdgcn_permlane32_swap(ulA[0], ulA[1], false, false);
    auto aA1 = __builtin_amdgcn_permlane32_swap(uhA[0], uhA[1], false, false);
    auto aA2 = __builtin_amdgcn_permlane32_swap(ulA[2], ulA[3], false, false);
    auto aA3 = __builtin_amdgcn_permlane32_swap(uhA[2], uhA[3], false, false);
    u32x4 wA0 = {aA0[0], aA1[0], aA0[1], aA1[1]};
    u32x4 wA1 = {aA2[0], aA3[0], aA2[1], aA3[1]};
    h8 pbA0 = __builtin_bit_cast(h8, wA0);   // keys 0..31 in permuted slots
    h8 pbA1 = __builtin_bit_cast(h8, wA1);   // keys 32..63

    // half B
    unsigned ulB[4], uhB[4];
#pragma unroll
    for (int g = 0; g < 4; ++g) {
      float p0 = __builtin_amdgcn_exp2f(sB[g][0]);
      float p1 = __builtin_amdgcn_exp2f(sB[g][1]);
      float p2 = __builtin_amdgcn_exp2f(sB[g][2]);
      float p3 = __builtin_amdgcn_exp2f(sB[g][3]);
      l_accB += (p0 + p1) + (p2 + p3);
      ulB[g] = __builtin_bit_cast(unsigned, __builtin_amdgcn_cvt_pkrtz(p0, p1));
      uhB[g] = __builtin_bit_cast(unsigned, __builtin_amdgcn_cvt_pkrtz(p2, p3));
    }
    auto aB0 = __builtin_amdgcn_permlane32_swap(ulB[0], ulB[1], false, false);
    auto aB1 = __builtin_amdgcn_permlane32_swap(uhB[0], uhB[1], false, false);
    auto aB2 = __builtin_amdgcn_permlane32_swap(ulB[2], ulB[3], false, false);
    auto aB3 = __builtin_amdgcn_permlane32_swap(uhB[2], uhB[3], false, false);
    u32x4 wB0 = {aB0[0], aB1[0], aB0[1], aB1[1]};
    u32x4 wB1 = {aB2[0], aB3[0], aB2[1], aB3[1]};
    h8 pbB0 = __builtin_bit_cast(h8, wB0);
    h8 pbB1 = __builtin_bit_cast(h8, wB1);

    // PV: V-frags read with the matching nibble map (4x b64 per f), shared by halves
#pragma unroll
    for (int f = 0; f < 4; ++f) {
      const unsigned short* vr = Vl + (f * 16 + l16) * 64;
      u64x2 tva = { *(const unsigned long long*)(vr + vo0),
                    *(const unsigned long long*)(vr + vo1) };
      u64x2 tvb = { *(const unsigned long long*)(vr + vo2),
                    *(const unsigned long long*)(vr + vo3) };
      h8 v0 = __builtin_bit_cast(h8, tva);
      h8 v1 = __builtin_bit_cast(h8, tvb);
      ovA[f] = __builtin_amdgcn_mfma_f32_16x16x32_f16(v0, pbA0, ovA[f], 0, 0, 0);
      ovA[f] = __builtin_amdgcn_mfma_f32_16x16x32_f16(v1, pbA1, ovA[f], 0, 0, 0);
      ovB[f] = __builtin_amdgcn_mfma_f32_16x16x32_f16(v0, pbB0, ovB[f], 0, 0, 0);
      ovB[f] = __builtin_amdgcn_mfma_f32_16x16x32_f16(v1, pbB1, ovB[f], 0, 0, 0);
    }
  }
  // l: reduce across quads (same query = l16)
  float ltA = l_accA;
  ltA += __shfl_xor(ltA, 16);
  ltA += __shfl_xor(ltA, 32);
  const float invA = 1.0f / ltA;
  float ltB = l_accB;
  ltB += __shfl_xor(ltB, 16);
  ltB += __shfl_xor(ltB, 32);
  const float invB = 1.0f / ltB;
  float* orowA = out + ((size_t)(b * SS + qsA + l16)) * SD + h * 64 + quad * 4;
  float* orowB = orowA + (size_t)64 * SD;
#pragma unroll
  for (int f = 0; f < 4; ++f) {
    float4 w;
    w.x = ovA[f][0] * invA; w.y = ovA[f][1] * invA;
    w.z = ovA[f][2] * invA; w.w = ovA[f][3] * invA;
    *(float4*)(orowA + f * 16) = w;
    float4 u;
    u.x = ovB[f][0] * invB; u.y = ovB[f][1] * invB;
    u.z = ovB[f][2] * invB; u.w = ovB[f][3] * invB;
    *(float4*)(orowB + f * 16) = u;
  }
}

extern "C" void kernel_launch(void* const* d_in, const int* in_sizes, int n_in,
                              void* d_out, int out_size, void* d_ws, size_t ws_size,
                              hipStream_t stream) {
  const float* hs = (const float*)d_in[0];
  const float* Wq = (const float*)d_in[1];
  const float* bq = (const float*)d_in[2];
  const float* Wk = (const float*)d_in[3];
  const float* bk = (const float*)d_in[4];
  const float* Wv = (const float*)d_in[5];
  const float* bv = (const float*)d_in[6];
  float* out = (float*)d_out;

  char* ws = (char*)d_ws;
  unsigned short* Xh  = (unsigned short*)(ws);
  unsigned short* Wqh = (unsigned short*)(ws + 16777216);
  unsigned short* Wkh = (unsigned short*)(ws + 16777216 + 2097152);
  unsigned short* Wvh = (unsigned short*)(ws + 16777216 + 2 * 2097152);
  unsigned short* Qh  = (unsigned short*)(ws + 16777216 + 3 * 2097152);
  unsigned short* Kh  = Qh + (size_t)SM * SD;
  unsigned short* Vt  = Kh + (size_t)SM * SD;

  cvt4h<<<dim3(8192), dim3(256), 0, stream>>>(hs, Xh, SM * SD / 4);
  cvt3w<<<dim3(1024, 3), dim3(256), 0, stream>>>(Wq, Wk, Wv, Wqh, Wkh, Wvh);
  gemm_qkv<<<dim3(1536), dim3(256), 0, stream>>>(
      Xh, Wqh, Wkh, Wvh, bq, bk, bv, Qh, Kh, Vt);
  attn<<<dim3(SB * SH * (SS / 128)), dim3(256), 0, stream>>>(Qh, Kh, Vt, out);
}

// Round 2
// 237.582 us; speedup vs baseline: 1.0576x; 1.0522x over previous
//
#include <hip/hip_runtime.h>
#include <math.h>

// Problem constants
#define SB 4
#define SS 2048
#define SD 1024
#define SH 16
#define SHD 64
#define SM (SB * SS) // 8192 rows

using f32x4 = __attribute__((ext_vector_type(4))) float;
using h8    = __attribute__((ext_vector_type(8))) _Float16;
using h4    = __attribute__((ext_vector_type(4))) _Float16;
using fp16x2 = __fp16 __attribute__((ext_vector_type(2)));
using fp16x4 = __fp16 __attribute__((ext_vector_type(4)));
using u32x4 = __attribute__((ext_vector_type(4))) unsigned int;

__device__ __forceinline__ unsigned short f2h(float x) {
  _Float16 h = (_Float16)x;
  return __builtin_bit_cast(unsigned short, h);
}

__device__ __forceinline__ void gld_lds16(const unsigned short* g, unsigned short* l) {
  __builtin_amdgcn_global_load_lds(
      (const __attribute__((address_space(1))) unsigned int*)g,
      (__attribute__((address_space(3))) unsigned int*)l, 16, 0, 0);
}

// ---------------- fp32 -> fp16 convert (4 elems/thread) ----------------
__global__ __launch_bounds__(256) void cvt4h(const float* __restrict__ in,
                                             unsigned short* __restrict__ out, int n4) {
  int i = blockIdx.x * 256 + threadIdx.x;
  if (i >= n4) return;
  float4 v = ((const float4*)in)[i];
  unsigned long long r = (unsigned long long)f2h(v.x)
                       | ((unsigned long long)f2h(v.y) << 16)
                       | ((unsigned long long)f2h(v.z) << 32)
                       | ((unsigned long long)f2h(v.w) << 48);
  ((unsigned long long*)out)[i] = r;
}

// three weight converts in one dispatch
__global__ __launch_bounds__(256) void cvt3w(const float* __restrict__ w0, const float* __restrict__ w1,
                                             const float* __restrict__ w2,
                                             unsigned short* __restrict__ o0, unsigned short* __restrict__ o1,
                                             unsigned short* __restrict__ o2) {
  const int z = blockIdx.y;
  const float* in = (z == 0) ? w0 : (z == 1) ? w1 : w2;
  unsigned short* out = (z == 0) ? o0 : (z == 1) ? o1 : o2;
  int i = blockIdx.x * 256 + threadIdx.x;
  float4 v = ((const float4*)in)[i];
  unsigned long long r = (unsigned long long)f2h(v.x)
                       | ((unsigned long long)f2h(v.y) << 16)
                       | ((unsigned long long)f2h(v.z) << 32)
                       | ((unsigned long long)f2h(v.w) << 48);
  ((unsigned long long*)out)[i] = r;
}

// ---------------- fused QKV projection GEMM, BK=64, XCD-swizzled ----------------
// z==0: Qh = (X@Wq^T + bq) * (1/8*log2e)  fp16, [s][1024]   (swapped-operand path)
// z==1: Kh =  X@Wk^T + bk                 fp16, [s][1024]   (swapped-operand path)
// z==2: Vt =  X@Wv^T + bv                 fp16, transposed [bh*64+d][s]
__global__ __launch_bounds__(256) void gemm_qkv(
    const unsigned short* __restrict__ Xh,
    const unsigned short* __restrict__ Wqh, const unsigned short* __restrict__ Wkh,
    const unsigned short* __restrict__ Wvh,
    const float* __restrict__ bq, const float* __restrict__ bk, const float* __restrict__ bv,
    unsigned short* __restrict__ Qh, unsigned short* __restrict__ Kh,
    unsigned short* __restrict__ Vt) {
  __shared__ unsigned short lA[128 * 64]; // 16 KB
  __shared__ unsigned short lB[128 * 64]; // 16 KB
  const int L = blockIdx.x;
  const int xcd = L & 7, rr = L >> 3;
  const int mloc = rr & 7, widx = rr >> 3;   // widx 0..23
  const int tNi = widx & 7, z = widx >> 3;   // z 0..2
  const int tM = (xcd * 8 + mloc) * 128, tN = tNi * 128;

  const unsigned short* W = (z == 0) ? Wqh : (z == 1) ? Wkh : Wvh;
  const float* bias = (z == 0) ? bq : (z == 1) ? bk : bv;

  const int tid = threadIdx.x;
  const int wave = tid >> 6, lane = tid & 63;
  const int quad = lane >> 4, l16 = lane & 15;
  const int wr = (wave >> 1) * 64, wc = (wave & 1) * 64;

  f32x4 acc[4][4] = {};

  const int rB = tid >> 3;
  const int colOff = (((tid & 7) ^ (rB & 7))) * 8;
  const unsigned short* gA[4];
  const unsigned short* gB[4];
#pragma unroll
  for (int i = 0; i < 4; ++i) {
    gA[i] = Xh + (size_t)(tM + i * 32 + rB) * SD + colOff;
    gB[i] = W  + (size_t)(tN + i * 32 + rB) * SD + colOff;
  }
  unsigned short* dA[4];
  unsigned short* dB[4];
#pragma unroll
  for (int i = 0; i < 4; ++i) {
    dA[i] = lA + (i * 256 + wave * 64) * 8;
    dB[i] = lB + (i * 256 + wave * 64) * 8;
  }
  const int swl = l16 & 7;

  if (z == 2) {
    for (int k0 = 0; k0 < SD; k0 += 64) {
      __syncthreads();
#pragma unroll
      for (int i = 0; i < 4; ++i) gld_lds16(gA[i] + k0, dA[i]);
#pragma unroll
      for (int i = 0; i < 4; ++i) gld_lds16(gB[i] + k0, dB[i]);
      __syncthreads();
#pragma unroll
      for (int ks = 0; ks < 2; ++ks) {
        h8 af[4], bf[4];
#pragma unroll
        for (int mi = 0; mi < 4; ++mi)
          af[mi] = *(const h8*)(lA + (wr + mi * 16 + l16) * 64 + (((ks * 4 + quad) ^ swl) * 8));
#pragma unroll
        for (int ni = 0; ni < 4; ++ni)
          bf[ni] = *(const h8*)(lB + (wc + ni * 16 + l16) * 64 + (((ks * 4 + quad) ^ swl) * 8));
#pragma unroll
        for (int mi = 0; mi < 4; ++mi)
#pragma unroll
          for (int ni = 0; ni < 4; ++ni)
            acc[mi][ni] = __builtin_amdgcn_mfma_f32_16x16x32_f16(af[mi], bf[ni], acc[mi][ni], 0, 0, 0);
      }
    }
    // C/D: col=l16 -> gn, row=quad*4+r -> gm (s-direction) ; pack r -> b64
#pragma unroll
    for (int ni = 0; ni < 4; ++ni) {
      const int gn = tN + wc + ni * 16 + l16;
      const float bb = bias[gn];
#pragma unroll
      for (int mi = 0; mi < 4; ++mi) {
        const int gm = tM + wr + mi * 16 + quad * 4;
        const int vb = gm >> 11, vs = gm & 2047;
        unsigned long long wv = 0;
#pragma unroll
        for (int r = 0; r < 4; ++r)
          wv |= (unsigned long long)f2h(acc[mi][ni][r] + bb) << (16 * r);
        *(unsigned long long*)(Vt + (size_t)(vb * 1024 + gn) * SS + vs) = wv;
      }
    }
  } else {
    // swapped operands: D m-dim = W rows (gn), n-dim = X rows (gm)
    for (int k0 = 0; k0 < SD; k0 += 64) {
      __syncthreads();
#pragma unroll
      for (int i = 0; i < 4; ++i) gld_lds16(gA[i] + k0, dA[i]);
#pragma unroll
      for (int i = 0; i < 4; ++i) gld_lds16(gB[i] + k0, dB[i]);
      __syncthreads();
#pragma unroll
      for (int ks = 0; ks < 2; ++ks) {
        h8 af[4], bf[4];
#pragma unroll
        for (int mi = 0; mi < 4; ++mi)
          af[mi] = *(const h8*)(lA + (wr + mi * 16 + l16) * 64 + (((ks * 4 + quad) ^ swl) * 8));
#pragma unroll
        for (int ni = 0; ni < 4; ++ni)
          bf[ni] = *(const h8*)(lB + (wc + ni * 16 + l16) * 64 + (((ks * 4 + quad) ^ swl) * 8));
#pragma unroll
        for (int mi = 0; mi < 4; ++mi)
#pragma unroll
          for (int ni = 0; ni < 4; ++ni)
            acc[mi][ni] = __builtin_amdgcn_mfma_f32_16x16x32_f16(bf[ni], af[mi], acc[mi][ni], 0, 0, 0);
      }
    }
    // C/D: col=l16 -> gm (X row), row=quad*4+r -> gn (consecutive!) -> b64 store
    const float sc = (z == 0) ? 0.18033688011112042f : 1.0f; // 1/8*log2(e)
    unsigned short* C = (z == 0) ? Qh : Kh;
#pragma unroll
    for (int mi = 0; mi < 4; ++mi) {
      const int gm = tM + wr + mi * 16 + l16;
#pragma unroll
      for (int ni = 0; ni < 4; ++ni) {
        const int gnb = tN + wc + ni * 16 + quad * 4;
        const float4 bb4 = *(const float4*)(bias + gnb);
        unsigned long long wv;
        wv  = (unsigned long long)f2h((acc[mi][ni][0] + bb4.x) * sc);
        wv |= (unsigned long long)f2h((acc[mi][ni][1] + bb4.y) * sc) << 16;
        wv |= (unsigned long long)f2h((acc[mi][ni][2] + bb4.z) * sc) << 32;
        wv |= (unsigned long long)f2h((acc[mi][ni][3] + bb4.w) * sc) << 48;
        *(unsigned long long*)(C + (size_t)gm * SD + gnb) = wv;
      }
    }
  }
}

// ---------------- attention: 256 q/block, 64 q/wave (4 half-tiles), P in-register ----
// S^T = K·Q^T (A=K-frag K=32, B=Q-frag) -> C: col=l16=query, row=nt*16+quad*4+r=key
// Canonical P redistribution: swap16(swap32(ul_g, ul_g+1)) lands keys 8q..8q+7 at
// lane quad q (the canonical B-operand layout), so V is consumed as plain b128
// chunk reads (conflict-free, same pattern as K) — no P LDS, no nibble reads.
// K/V fragment reads amortized over 4 query half-tiles (64 q/wave).
__global__ __launch_bounds__(256, 2) void attn(const unsigned short* __restrict__ Qh,
                                               const unsigned short* __restrict__ Kh,
                                               const unsigned short* __restrict__ Vt,
                                               float* __restrict__ out) {
  __shared__ unsigned short lK[2][64 * 64]; // 16 KB
  __shared__ unsigned short lV[2][64 * 64]; // 16 KB  (32 KB total)
  const int tid = threadIdx.x;
  const int wave = tid >> 6, lane = tid & 63;
  const int quad = lane >> 4, l16 = lane & 15;
  // grid 512: bid = qt*64 + bh -> all 8 q-tiles of one bh share an XCD (bid%8==bh%8)
  const int bid = blockIdx.x;
  const int bh = bid & 63, qt = bid >> 6;          // qt 0..7
  const int b = bh >> 4, h = bh & 15;
  const int qs = qt * 256 + wave * 16;             // halves at +0,+64,+128,+192

  const unsigned short* qp0 = Qh + ((size_t)(b * SS + qs + l16)) * SD + h * 64 + quad * 8;
  h8 aq[4][2];
#pragma unroll
  for (int x = 0; x < 4; ++x) {
    aq[x][0] = *(const h8*)(qp0 + (size_t)(x * 64) * SD);
    aq[x][1] = *(const h8*)(qp0 + (size_t)(x * 64) * SD + 32);
  }

  const int row0 = tid >> 3, cs0 = (tid & 7) ^ (row0 & 7);
  const int row1 = row0 + 32, cs1 = (tid & 7) ^ (row1 & 7);
  const unsigned short* kS0 = Kh + ((size_t)(b * SS + row0)) * SD + h * 64 + cs0 * 8;
  const unsigned short* kS1 = Kh + ((size_t)(b * SS + row1)) * SD + h * 64 + cs1 * 8;
  const unsigned short* vS0 = Vt + ((size_t)(bh * 64 + row0)) * SS + cs0 * 8;
  const unsigned short* vS1 = Vt + ((size_t)(bh * 64 + row1)) * SS + cs1 * 8;
  unsigned short* dK0 = &lK[0][wave * 512];
  unsigned short* dK1 = &lK[0][2048 + wave * 512];
  unsigned short* dV0 = &lV[0][wave * 512];
  unsigned short* dV1 = &lV[0][2048 + wave * 512];

  f32x4 ov[4][4] = {};
  float lacc[4] = {0.f, 0.f, 0.f, 0.f};
  const int swl = l16 & 7;
  const int ko0 = (quad ^ swl) * 8, ko1 = ((4 + quad) ^ swl) * 8;

  gld_lds16(kS0, dK0); gld_lds16(kS1, dK1);
  gld_lds16(vS0, dV0); gld_lds16(vS1, dV1);
  kS0 += 64 * SD; kS1 += 64 * SD; vS0 += 64; vS1 += 64;

  for (int kt = 0; kt < 32; ++kt) {
    const int buf = kt & 1;
    __syncthreads();
    if (kt < 31) {
      const int o = (buf ^ 1) * 64 * 64;
      gld_lds16(kS0, dK0 + o); gld_lds16(kS1, dK1 + o);
      gld_lds16(vS0, dV0 + o); gld_lds16(vS1, dV1 + o);
      kS0 += 64 * SD; kS1 += 64 * SD; vS0 += 64; vS1 += 64;
    }
    const unsigned short* Kt = lK[buf];
    const unsigned short* Vl = lV[buf];

    // QK^T: 32 MFMA K=32; K-frags shared by all 4 query half-tiles
    f32x4 s[4][4]; // [half][nt]
#pragma unroll
    for (int nt = 0; nt < 4; ++nt) {
      const unsigned short* kr = Kt + (nt * 16 + l16) * 64;
      h8 kf0 = *(const h8*)(kr + ko0);
      h8 kf1 = *(const h8*)(kr + ko1);
#pragma unroll
      for (int x = 0; x < 4; ++x) {
        f32x4 z = {};
        z = __builtin_amdgcn_mfma_f32_16x16x32_f16(kf0, aq[x][0], z, 0, 0, 0);
        s[x][nt] = __builtin_amdgcn_mfma_f32_16x16x32_f16(kf1, aq[x][1], z, 0, 0, 0);
      }
    }

    // softmax + canonical in-register redistribution, per half
    h8 pb[4][2];
#pragma unroll
    for (int x = 0; x < 4; ++x) {
      unsigned ul[4], uh[4];
      float la = 0.f;
#pragma unroll
      for (int g = 0; g < 4; ++g) {
        float p0 = __builtin_amdgcn_exp2f(s[x][g][0]);
        float p1 = __builtin_amdgcn_exp2f(s[x][g][1]);
        float p2 = __builtin_amdgcn_exp2f(s[x][g][2]);
        float p3 = __builtin_amdgcn_exp2f(s[x][g][3]);
        la += (p0 + p1) + (p2 + p3);
        ul[g] = __builtin_bit_cast(unsigned, __builtin_amdgcn_cvt_pkrtz(p0, p1));
        uh[g] = __builtin_bit_cast(unsigned, __builtin_amdgcn_cvt_pkrtz(p2, p3));
      }
      lacc[x] += la;
      // keys 0..31 -> canonical slots: quad q holds keys 8q..8q+7
      auto sl0 = __builtin_amdgcn_permlane32_swap(ul[0], ul[1], false, false);
      auto tl0 = __builtin_amdgcn_permlane16_swap(sl0[0], sl0[1], false, false);
      auto sh0 = __builtin_amdgcn_permlane32_swap(uh[0], uh[1], false, false);
      auto th0 = __builtin_amdgcn_permlane16_swap(sh0[0], sh0[1], false, false);
      u32x4 w0 = {tl0[0], th0[0], tl0[1], th0[1]};
      pb[x][0] = __builtin_bit_cast(h8, w0);
      // keys 32..63
      auto sl1 = __builtin_amdgcn_permlane32_swap(ul[2], ul[3], false, false);
      auto tl1 = __builtin_amdgcn_permlane16_swap(sl1[0], sl1[1], false, false);
      auto sh1 = __builtin_amdgcn_permlane32_swap(uh[2], uh[3], false, false);
      auto th1 = __builtin_amdgcn_permlane16_swap(sh1[0], sh1[1], false, false);
      u32x4 w1 = {tl1[0], th1[0], tl1[1], th1[1]};
      pb[x][1] = __builtin_bit_cast(h8, w1);
    }

    // PV: canonical b128 V-frag reads (conflict-free), shared by all 4 halves
#pragma unroll
    for (int f = 0; f < 4; ++f) {
      const unsigned short* vr = Vl + (f * 16 + l16) * 64;
      h8 v0 = *(const h8*)(vr + ko0);
      h8 v1 = *(const h8*)(vr + ko1);
#pragma unroll
      for (int x = 0; x < 4; ++x) {
        ov[x][f] = __builtin_amdgcn_mfma_f32_16x16x32_f16(v0, pb[x][0], ov[x][f], 0, 0, 0);
        ov[x][f] = __builtin_amdgcn_mfma_f32_16x16x32_f16(v1, pb[x][1], ov[x][f], 0, 0, 0);
      }
    }
  }

  // epilogue: l reduce across quads (same query = l16), normalize, store
#pragma unroll
  for (int x = 0; x < 4; ++x) {
    float lt = lacc[x];
    lt += __shfl_xor(lt, 16);
    lt += __shfl_xor(lt, 32);
    const float inv = 1.0f / lt;
    float* orow = out + ((size_t)(b * SS + qs + x * 64 + l16)) * SD + h * 64 + quad * 4;
#pragma unroll
    for (int f = 0; f < 4; ++f) {
      float4 w;
      w.x = ov[x][f][0] * inv; w.y = ov[x][f][1] * inv;
      w.z = ov[x][f][2] * inv; w.w = ov[x][f][3] * inv;
      *(float4*)(orow + f * 16) = w;
    }
  }
}

extern "C" void kernel_launch(void* const* d_in, const int* in_sizes, int n_in,
                              void* d_out, int out_size, void* d_ws, size_t ws_size,
                              hipStream_t stream) {
  const float* hs = (const float*)d_in[0];
  const float* Wq = (const float*)d_in[1];
  const float* bq = (const float*)d_in[2];
  const float* Wk = (const float*)d_in[3];
  const float* bk = (const float*)d_in[4];
  const float* Wv = (const float*)d_in[5];
  const float* bv = (const float*)d_in[6];
  float* out = (float*)d_out;

  char* ws = (char*)d_ws;
  unsigned short* Xh  = (unsigned short*)(ws);
  unsigned short* Wqh = (unsigned short*)(ws + 16777216);
  unsigned short* Wkh = (unsigned short*)(ws + 16777216 + 2097152);
  unsigned short* Wvh = (unsigned short*)(ws + 16777216 + 2 * 2097152);
  unsigned short* Qh  = (unsigned short*)(ws + 16777216 + 3 * 2097152);
  unsigned short* Kh  = Qh + (size_t)SM * SD;
  unsigned short* Vt  = Kh + (size_t)SM * SD;

  cvt4h<<<dim3(8192), dim3(256), 0, stream>>>(hs, Xh, SM * SD / 4);
  cvt3w<<<dim3(1024, 3), dim3(256), 0, stream>>>(Wq, Wk, Wv, Wqh, Wkh, Wvh);
  gemm_qkv<<<dim3(1536), dim3(256), 0, stream>>>(
      Xh, Wqh, Wkh, Wvh, bq, bk, bv, Qh, Kh, Vt);
  attn<<<dim3(SB * SH * (SS / 256)), dim3(256), 0, stream>>>(Qh, Kh, Vt, out);
}